// Round 7
// baseline (403.831 us; speedup 1.0000x reference)
//
#include <hip/hip_runtime.h>
#include <hip/hip_bf16.h>
#include <math.h>

// Problem constants
#define IN_DIM   384
#define GNN_DIM  256
#define HEADS    4
#define DH       64
#define N_PATCH  8192
#define N_TILES  128
#define N_EDGES  1024
#define N_TOT    (N_PATCH + N_TILES)   // 8320
#define ROWS_A   16                    // rows per block in phaseA
#define NCHUNK   8                     // node chunks in phaseC
#define CHSZ     1040                  // nodes per chunk (8*1040 = 8320)
#define NTB      (N_TOT / 8)           // 1040 bytes per HTb row
#define NEB      (N_EDGES / 8)         // 128 bytes per HNb row

// ---------------------------------------------------------------------------
__device__ __forceinline__ float waveReduce(float v) {
    #pragma unroll
    for (int o = 32; o > 0; o >>= 1) v += __shfl_down(v, o, 64);
    return v; // valid in lane 0 of each 64-wide wave
}

// ---------------------------------------------------------------------------
// Binarize + transpose H [N_TOT, N_EDGES] f32 into bit-packed masks:
//   HTb [E][N_TOT/8]  (edge-major, for phaseC)
//   HNb [N][N_EDGES/8] (node-major, for phaseE)
// ---------------------------------------------------------------------------
__global__ __launch_bounds__(256) void transposeH(
    const float* __restrict__ H,
    unsigned char* __restrict__ HTb, unsigned char* __restrict__ HNb)
{
    __shared__ unsigned char t[32][33];   // t[node][edge]
    int n0 = blockIdx.x * 32;
    int e0 = blockIdx.y * 32;
    int tx = threadIdx.x & 31, ty = threadIdx.x >> 5;  // ty in 0..7
    #pragma unroll
    for (int r = 0; r < 4; ++r) {
        int row = ty + r * 8;
        t[row][tx] = (H[(size_t)(n0 + row) * N_EDGES + e0 + tx] > 0.f) ? 1 : 0;
    }
    __syncthreads();
    int tid = threadIdx.x;
    if (tid < 128) {            // HTb: 32 edges x 4 node-bytes
        int er = tid >> 2, g = tid & 3;
        unsigned v = 0;
        #pragma unroll
        for (int i = 0; i < 8; ++i) v |= (unsigned)t[g * 8 + i][er] << i;
        HTb[(size_t)(e0 + er) * NTB + (n0 >> 3) + g] = (unsigned char)v;
    } else {                    // HNb: 32 nodes x 4 edge-bytes
        int id = tid - 128;
        int nr = id >> 2, g = id & 3;
        unsigned v = 0;
        #pragma unroll
        for (int i = 0; i < 8; ++i) v |= (unsigned)t[nr][g * 8 + i] << i;
        HNb[(size_t)(n0 + nr) * NEB + (e0 >> 3) + g] = (unsigned char)v;
    }
}

// ---------------------------------------------------------------------------
// Phase A: h = X @ W + nemb[node_type]; fused s_src/s_dst dots and
// expL[n,t,h] = exp(leaky_relu(s_src + ebias[t,h])).
// 16 rows per block: W element loaded once, reused 16x.
// Also emits bf16 shadow hPb for the phaseC gather.
// ---------------------------------------------------------------------------
__global__ __launch_bounds__(256) void phaseA(
    const float* __restrict__ x0,      // layer0 node features (or null)
    const float* __restrict__ readout, // layer0 readout token [384]
    const float* __restrict__ xf,      // layer1 input (or null)
    int K,
    const float* __restrict__ W,       // [K,256]
    const float* __restrict__ nemb,    // [4,256]
    const int* __restrict__ node_type,
    const float* __restrict__ asrc,    // [4,64]
    const float* __restrict__ adst,    // [4,64]
    const float* __restrict__ ebias,   // [3,4]
    float* __restrict__ hP, __hip_bfloat16* __restrict__ hPb,
    float* __restrict__ expL, float* __restrict__ sdst)
{
    __shared__ float xs[IN_DIM][ROWS_A];   // transposed X tile: 24 KB max
    int n0 = blockIdx.x * ROWS_A, j = threadIdx.x;
    #pragma unroll
    for (int r = 0; r < ROWS_A; ++r) {
        int n = n0 + r;
        for (int k = j; k < K; k += 256) {
            float v;
            if (xf)               v = xf[(size_t)n * K + k];
            else if (n < N_PATCH) v = x0[(size_t)n * K + k];
            else                  v = readout[k];
            xs[k][r] = v;
        }
    }
    __syncthreads();

    float acc[ROWS_A];
    #pragma unroll
    for (int r = 0; r < ROWS_A; ++r) acc[r] = 0.f;
    for (int k = 0; k < K; ++k) {
        float w = W[(size_t)k * GNN_DIM + j];
        #pragma unroll
        for (int r = 0; r < ROWS_A; ++r) acc[r] += xs[k][r] * w;
    }

    int h = j >> 6, lane = j & 63;
    float as = asrc[h * DH + lane];
    float ad = adst[h * DH + lane];
    float eb0 = ebias[0 * HEADS + h], eb1 = ebias[1 * HEADS + h], eb2 = ebias[2 * HEADS + h];
    #pragma unroll
    for (int r = 0; r < ROWS_A; ++r) {
        int n = n0 + r;
        float hv = acc[r] + nemb[node_type[n] * GNN_DIM + j];
        hP[(size_t)n * GNN_DIM + j] = hv;
        hPb[(size_t)n * GNN_DIM + j] = __float2bfloat16(hv);
        float ss = waveReduce(hv * as);
        float sd = waveReduce(hv * ad);
        if (lane == 0) {
            sdst[n * HEADS + h] = sd;
            float l0 = ss + eb0; l0 = l0 > 0.f ? l0 : 0.2f * l0;
            float l1 = ss + eb1; l1 = l1 > 0.f ? l1 : 0.2f * l1;
            float l2 = ss + eb2; l2 = l2 > 0.f ? l2 : 0.2f * l2;
            expL[n * 12 + 0 * HEADS + h] = __expf(l0);
            expL[n * 12 + 1 * HEADS + h] = __expf(l1);
            expL[n * 12 + 2 * HEADS + h] = __expf(l2);
        }
    }
}

// ---------------------------------------------------------------------------
// Phase C accumulate: block (chunk, e); bit-mask compaction + bf16 gather.
// ---------------------------------------------------------------------------
__global__ __launch_bounds__(256) void phaseC_acc(
    const unsigned char* __restrict__ HTb,   // [E, N_TOT/8] bits
    const int* __restrict__ edge_type,
    const float* __restrict__ expL,          // [N,3,4]
    const __hip_bfloat16* __restrict__ hPb,  // [N,256] bf16
    float* __restrict__ macc,                // [NCHUNK,1024,256]
    float* __restrict__ Zacc)                // [NCHUNK,1024,4]
{
    int bid = blockIdx.x;
    int chunk = bid >> 10, e = bid & 1023;
    int nbase = chunk * CHSZ;
    int j = threadIdx.x, h = j >> 6, lane = j & 63;
    int te = edge_type[e];
    __shared__ int cnt;
    __shared__ int   nidx[256];
    __shared__ float wlds[256 * 4];
    if (j == 0) cnt = 0;
    __syncthreads();
    if (j < CHSZ / 8) {
        unsigned b = HTb[(size_t)e * NTB + chunk * (CHSZ / 8) + j];
        while (b) {
            int i = __ffs(b) - 1;
            b &= b - 1;
            int p = atomicAdd(&cnt, 1);
            nidx[p] = nbase + j * 8 + i;
        }
    }
    __syncthreads();
    int c = cnt;
    for (int i = j; i < c; i += 256)
        *(float4*)&wlds[i * 4] = *(const float4*)&expL[nidx[i] * 12 + te * 4];
    __syncthreads();

    float a0 = 0.f, a1 = 0.f, a2 = 0.f, a3 = 0.f;
    float Z0 = 0.f, Z1 = 0.f, Z2 = 0.f, Z3 = 0.f;
    int i = 0;
    for (; i + 3 < c; i += 4) {
        int m0 = nidx[i], m1 = nidx[i+1], m2 = nidx[i+2], m3 = nidx[i+3];
        float w0 = wlds[i * 4 + h],     w1 = wlds[(i+1) * 4 + h];
        float w2 = wlds[(i+2) * 4 + h], w3 = wlds[(i+3) * 4 + h];
        a0 += w0 * (float)hPb[(size_t)m0 * GNN_DIM + j];
        a1 += w1 * (float)hPb[(size_t)m1 * GNN_DIM + j];
        a2 += w2 * (float)hPb[(size_t)m2 * GNN_DIM + j];
        a3 += w3 * (float)hPb[(size_t)m3 * GNN_DIM + j];
        Z0 += w0; Z1 += w1; Z2 += w2; Z3 += w3;
    }
    for (; i < c; ++i) {
        int mm = nidx[i];
        float w = wlds[i * 4 + h];
        Z0 += w;
        a0 += w * (float)hPb[(size_t)mm * GNN_DIM + j];
    }
    macc[(size_t)bid * GNN_DIM + j] = ((a0 + a1) + (a2 + a3));
    if (lane == 0) Zacc[bid * HEADS + h] = (Z0 + Z1) + (Z2 + Z3);
}

// ---------------------------------------------------------------------------
// Phase C reduce: combine NCHUNK partials, normalize, emit bf16 m + sedg.
// ---------------------------------------------------------------------------
__global__ __launch_bounds__(256) void phaseC_red(
    const float* __restrict__ macc,    // [NCHUNK,1024,256]
    const float* __restrict__ Zacc,    // [NCHUNK,1024,4]
    const float* __restrict__ aedg,    // [4,64]
    __hip_bfloat16* __restrict__ mb, float* __restrict__ sedg)
{
    int e = blockIdx.x, j = threadIdx.x, h = j >> 6, lane = j & 63;
    float s = 0.f, Z = 0.f;
    #pragma unroll
    for (int c = 0; c < NCHUNK; ++c) {
        s += macc[(size_t)((c << 10) + e) * GNN_DIM + j];
        Z += Zacc[((c << 10) + e) * HEADS + h];
    }
    float mv = s / Z;
    mb[(size_t)e * GNN_DIM + j] = __float2bfloat16(mv);
    float se = waveReduce(mv * aedg[h * DH + lane]);
    if (lane == 0) sedg[e * HEADS + h] = se;
}

// ---------------------------------------------------------------------------
// Phase E: edge->node attention + ELU + residual. One block per node.
// Bit-mask edge compaction (HNb), bf16 m gather, f32 residual.
// ---------------------------------------------------------------------------
__global__ __launch_bounds__(256) void phaseE(
    const unsigned char* __restrict__ HNb,   // [N, E/8] bits
    const float* __restrict__ sdstArr,       // [N,4]
    const float* __restrict__ sedg,          // [E,4]
    const __hip_bfloat16* __restrict__ mb,   // [E,256] bf16
    const float* __restrict__ hP,            // [N,256] residual
    float* __restrict__ hOut)
{
    int n = blockIdx.x, j = threadIdx.x, h = j >> 6;
    __shared__ int cnt;
    __shared__ int   eidx[N_EDGES];          // 4 KB
    __shared__ float wlds[N_EDGES * 4];      // 16 KB (worst case)
    __shared__ float sdv[4];
    if (j < 4) sdv[j] = sdstArr[n * HEADS + j];
    if (j == 0) cnt = 0;
    __syncthreads();
    if (j < NEB) {
        unsigned b = HNb[(size_t)n * NEB + j];
        while (b) {
            int i = __ffs(b) - 1;
            b &= b - 1;
            int p = atomicAdd(&cnt, 1);
            eidx[p] = j * 8 + i;
        }
    }
    __syncthreads();
    int c = cnt;
    for (int i = j; i < c; i += 256) {
        int e = eidx[i];
        #pragma unroll
        for (int hh = 0; hh < HEADS; ++hh) {
            float l = sdv[hh] + sedg[e * HEADS + hh];
            l = l > 0.f ? l : 0.2f * l;
            wlds[i * 4 + hh] = __expf(l);
        }
    }
    __syncthreads();

    float a0 = 0.f, a1 = 0.f, a2 = 0.f, a3 = 0.f;
    float Z0 = 0.f, Z1 = 0.f, Z2 = 0.f, Z3 = 0.f;
    int i = 0;
    for (; i + 3 < c; i += 4) {
        int e_0 = eidx[i], e_1 = eidx[i+1], e_2 = eidx[i+2], e_3 = eidx[i+3];
        float w0 = wlds[i * 4 + h],     w1 = wlds[(i+1) * 4 + h];
        float w2 = wlds[(i+2) * 4 + h], w3 = wlds[(i+3) * 4 + h];
        a0 += w0 * (float)mb[(size_t)e_0 * GNN_DIM + j];
        a1 += w1 * (float)mb[(size_t)e_1 * GNN_DIM + j];
        a2 += w2 * (float)mb[(size_t)e_2 * GNN_DIM + j];
        a3 += w3 * (float)mb[(size_t)e_3 * GNN_DIM + j];
        Z0 += w0; Z1 += w1; Z2 += w2; Z3 += w3;
    }
    for (; i < c; ++i) {
        int ee = eidx[i];
        float w = wlds[i * 4 + h];
        Z0 += w;
        a0 += w * (float)mb[(size_t)ee * GNN_DIM + j];
    }
    float Z = (Z0 + Z1) + (Z2 + Z3);
    float o = ((a0 + a1) + (a2 + a3)) / Z;
    o = o > 0.f ? o : expm1f(o);   // ELU (alpha=1)
    hOut[(size_t)n * GNN_DIM + j] = o + hP[(size_t)n * GNN_DIM + j];
}

// ---------------------------------------------------------------------------
// Final layernorms -> f32 output, concatenated [8192*256, 128*256].
// ---------------------------------------------------------------------------
__global__ __launch_bounds__(256) void finalLN(
    const float* __restrict__ hX,
    const int* __restrict__ ro_ids,
    const float* __restrict__ ng, const float* __restrict__ nb,
    const float* __restrict__ bg, const float* __restrict__ bb,
    float* __restrict__ out)
{
    int r = blockIdx.x, j = threadIdx.x;
    int srcRow; const float *g, *b; size_t outOff;
    if (r < N_PATCH) { srcRow = r; g = ng; b = nb; outOff = (size_t)r * GNN_DIM; }
    else {
        int q = r - N_PATCH;
        srcRow = ro_ids[q]; g = bg; b = bb;
        outOff = (size_t)N_PATCH * GNN_DIM + (size_t)q * GNN_DIM;
    }
    float x = hX[(size_t)srcRow * GNN_DIM + j];
    __shared__ float red[4];
    int h = j >> 6, lane = j & 63;
    float s = waveReduce(x);
    if (lane == 0) red[h] = s;
    __syncthreads();
    float mean = (red[0] + red[1] + red[2] + red[3]) * (1.f / GNN_DIM);
    __syncthreads();
    float d = x - mean;
    float s2 = waveReduce(d * d);
    if (lane == 0) red[h] = s2;
    __syncthreads();
    float var = (red[0] + red[1] + red[2] + red[3]) * (1.f / GNN_DIM);
    float y = d * rsqrtf(var + 1e-5f) * g[j] + b[j];
    out[outOff + j] = y;
}

// ---------------------------------------------------------------------------
extern "C" void kernel_launch(void* const* d_in, const int* in_sizes, int n_in,
                              void* d_out, int out_size, void* d_ws, size_t ws_size,
                              hipStream_t stream) {
    const float* x_nodes   = (const float*)d_in[0];
    const float* readout   = (const float*)d_in[1];
    const int*   node_type = (const int*)d_in[2];
    const int*   edge_type = (const int*)d_in[3];
    const float* Hmat      = (const float*)d_in[4];
    const int*   ro_ids    = (const int*)d_in[5];
    const float* W0        = (const float*)d_in[6];
    const float* W1        = (const float*)d_in[7];
    const float* node_emb  = (const float*)d_in[8];
    const float* a_src     = (const float*)d_in[9];
    const float* a_dst     = (const float*)d_in[10];
    const float* a_edge    = (const float*)d_in[11];
    const float* edge_bias = (const float*)d_in[12];
    const float* node_g    = (const float*)d_in[13];
    const float* node_b    = (const float*)d_in[14];
    const float* bag_g     = (const float*)d_in[15];
    const float* bag_b     = (const float*)d_in[16];

    // Workspace layout (~25 MB). macc aliases hX (dead during phaseC;
    // 8.39 MB <= 8.52 MB).
    char* ws = (char*)d_ws;
    size_t off = 0;
    unsigned char* HTb = (unsigned char*)(ws + off); off += (size_t)N_EDGES * NTB;   // 1.06 MB
    unsigned char* HNb = (unsigned char*)(ws + off); off += (size_t)N_TOT * NEB;     // 1.06 MB
    off = (off + 255) & ~(size_t)255;
    float* hP   = (float*)(ws + off); off += (size_t)N_TOT * GNN_DIM * 4;            // 8.52 MB
    float* hX   = (float*)(ws + off); off += (size_t)N_TOT * GNN_DIM * 4;            // 8.52 MB
    __hip_bfloat16* hPb = (__hip_bfloat16*)(ws + off); off += (size_t)N_TOT * GNN_DIM * 2; // 4.26 MB
    __hip_bfloat16* mb  = (__hip_bfloat16*)(ws + off); off += (size_t)N_EDGES * GNN_DIM * 2;
    float* expL = (float*)(ws + off); off += (size_t)N_TOT * 12 * 4;
    float* sdst = (float*)(ws + off); off += (size_t)N_TOT * HEADS * 4;
    float* sedg = (float*)(ws + off); off += (size_t)N_EDGES * HEADS * 4;
    float* Zacc = (float*)(ws + off); off += (size_t)NCHUNK * 1024 * HEADS * 4;
    float* macc = hX;  // alias (see note above)

    dim3 gT(N_TOT / 32, N_EDGES / 32);
    transposeH<<<gT, 256, 0, stream>>>(Hmat, HTb, HNb);

    // ----- layer 0 -----
    phaseA<<<N_TOT / ROWS_A, 256, 0, stream>>>(x_nodes, readout, nullptr, IN_DIM,
                                      W0, node_emb, node_type,
                                      a_src, a_dst, edge_bias,
                                      hP, hPb, expL, sdst);
    phaseC_acc<<<NCHUNK * 1024, 256, 0, stream>>>(HTb, edge_type, expL, hPb, macc, Zacc);
    phaseC_red<<<N_EDGES, 256, 0, stream>>>(macc, Zacc, a_edge, mb, sedg);
    phaseE<<<N_TOT, 256, 0, stream>>>(HNb, sdst, sedg, mb, hP, hX);

    // ----- layer 1 -----
    phaseA<<<N_TOT / ROWS_A, 256, 0, stream>>>(nullptr, nullptr, hX, GNN_DIM,
                                      W1, node_emb + 4 * GNN_DIM, node_type,
                                      a_src + HEADS * DH, a_dst + HEADS * DH,
                                      edge_bias + 12,
                                      hP, hPb, expL, sdst);
    phaseC_acc<<<NCHUNK * 1024, 256, 0, stream>>>(HTb, edge_type, expL, hPb, macc, Zacc);
    phaseC_red<<<N_EDGES, 256, 0, stream>>>(macc, Zacc, a_edge + HEADS * DH, mb, sedg);
    phaseE<<<N_TOT, 256, 0, stream>>>(HNb, sdst, sedg, mb, hP, hX);

    finalLN<<<N_TOT, 256, 0, stream>>>(hX, ro_ids, node_g, node_b, bag_g, bag_b,
                                       (float*)d_out);
}

// Round 8
// 358.669 us; speedup vs baseline: 1.1259x; 1.1259x over previous
//
#include <hip/hip_runtime.h>
#include <hip/hip_bf16.h>
#include <math.h>

// Problem constants
#define IN_DIM   384
#define GNN_DIM  256
#define HEADS    4
#define DH       64
#define N_PATCH  8192
#define N_TILES  128
#define N_EDGES  1024
#define N_TOT    (N_PATCH + N_TILES)   // 8320
#define ROWS_A   8                     // rows per block in phaseA
#define NCHUNK   8                     // node chunks in phaseC
#define CHSZ     1040                  // nodes per chunk (8*1040 = 8320)
#define NTB      (N_TOT / 8)           // 1040 bytes per HTb row
#define NEB      (N_EDGES / 8)         // 128 bytes per HNb row

// ---------------------------------------------------------------------------
__device__ __forceinline__ float waveReduce(float v) {
    #pragma unroll
    for (int o = 32; o > 0; o >>= 1) v += __shfl_down(v, o, 64);
    return v; // valid in lane 0 of each 64-wide wave
}

// ---------------------------------------------------------------------------
// Binarize + transpose H [N_TOT, N_EDGES] f32 into bit-packed masks:
//   HTb [E][N_TOT/8]  (edge-major, for phaseC)
//   HNb [N][N_EDGES/8] (node-major, for phaseE)
// ---------------------------------------------------------------------------
__global__ __launch_bounds__(256) void transposeH(
    const float* __restrict__ H,
    unsigned char* __restrict__ HTb, unsigned char* __restrict__ HNb)
{
    __shared__ unsigned char t[32][33];   // t[node][edge]
    int n0 = blockIdx.x * 32;
    int e0 = blockIdx.y * 32;
    int tx = threadIdx.x & 31, ty = threadIdx.x >> 5;  // ty in 0..7
    #pragma unroll
    for (int r = 0; r < 4; ++r) {
        int row = ty + r * 8;
        t[row][tx] = (H[(size_t)(n0 + row) * N_EDGES + e0 + tx] > 0.f) ? 1 : 0;
    }
    __syncthreads();
    int tid = threadIdx.x;
    if (tid < 128) {            // HTb: 32 edges x 4 node-bytes
        int er = tid >> 2, g = tid & 3;
        unsigned v = 0;
        #pragma unroll
        for (int i = 0; i < 8; ++i) v |= (unsigned)t[g * 8 + i][er] << i;
        HTb[(size_t)(e0 + er) * NTB + (n0 >> 3) + g] = (unsigned char)v;
    } else {                    // HNb: 32 nodes x 4 edge-bytes
        int id = tid - 128;
        int nr = id >> 2, g = id & 3;
        unsigned v = 0;
        #pragma unroll
        for (int i = 0; i < 8; ++i) v |= (unsigned)t[nr][g * 8 + i] << i;
        HNb[(size_t)(n0 + nr) * NEB + (e0 >> 3) + g] = (unsigned char)v;
    }
}

// ---------------------------------------------------------------------------
// Phase A: h = X @ W + nemb[node_type]; fused s_src/s_dst dots and
// expL[n,t,h] = exp(leaky_relu(s_src + ebias[t,h])).
// 8 rows per block (grid 1040 -> 4 blocks/CU). X tile stored as two float4
// LDS arrays (rows 0..3 / 4..7 per k) -> inner loop is 2x ds_read_b128
// broadcast + 1 W load + 8 FMA, no bank conflicts.
// ---------------------------------------------------------------------------
__global__ __launch_bounds__(256) void phaseA(
    const float* __restrict__ x0,      // layer0 node features (or null)
    const float* __restrict__ readout, // layer0 readout token [384]
    const float* __restrict__ xf,      // layer1 input (or null)
    int K,
    const float* __restrict__ W,       // [K,256]
    const float* __restrict__ nemb,    // [4,256]
    const int* __restrict__ node_type,
    const float* __restrict__ asrc,    // [4,64]
    const float* __restrict__ adst,    // [4,64]
    const float* __restrict__ ebias,   // [3,4]
    float* __restrict__ hP, __hip_bfloat16* __restrict__ hPb,
    float* __restrict__ expL, float* __restrict__ sdst)
{
    __shared__ float4 xsA[IN_DIM];   // rows 0..3 for each k
    __shared__ float4 xsB[IN_DIM];   // rows 4..7 for each k
    int n0 = blockIdx.x * ROWS_A, j = threadIdx.x;
    for (int k = j; k < K; k += 256) {
        float v[ROWS_A];
        #pragma unroll
        for (int r = 0; r < ROWS_A; ++r) {
            int n = n0 + r;
            if (xf)               v[r] = xf[(size_t)n * K + k];
            else if (n < N_PATCH) v[r] = x0[(size_t)n * K + k];
            else                  v[r] = readout[k];
        }
        xsA[k] = make_float4(v[0], v[1], v[2], v[3]);
        xsB[k] = make_float4(v[4], v[5], v[6], v[7]);
    }
    __syncthreads();

    float acc[ROWS_A];
    #pragma unroll
    for (int r = 0; r < ROWS_A; ++r) acc[r] = 0.f;
    for (int k = 0; k < K; ++k) {
        float w = W[(size_t)k * GNN_DIM + j];
        float4 a = xsA[k], b = xsB[k];
        acc[0] += a.x * w; acc[1] += a.y * w; acc[2] += a.z * w; acc[3] += a.w * w;
        acc[4] += b.x * w; acc[5] += b.y * w; acc[6] += b.z * w; acc[7] += b.w * w;
    }

    int h = j >> 6, lane = j & 63;
    float as = asrc[h * DH + lane];
    float ad = adst[h * DH + lane];
    float eb0 = ebias[0 * HEADS + h], eb1 = ebias[1 * HEADS + h], eb2 = ebias[2 * HEADS + h];
    #pragma unroll
    for (int r = 0; r < ROWS_A; ++r) {
        int n = n0 + r;
        float hv = acc[r] + nemb[node_type[n] * GNN_DIM + j];
        hP[(size_t)n * GNN_DIM + j] = hv;
        hPb[(size_t)n * GNN_DIM + j] = __float2bfloat16(hv);
        float ss = waveReduce(hv * as);
        float sd = waveReduce(hv * ad);
        if (lane == 0) {
            sdst[n * HEADS + h] = sd;
            float l0 = ss + eb0; l0 = l0 > 0.f ? l0 : 0.2f * l0;
            float l1 = ss + eb1; l1 = l1 > 0.f ? l1 : 0.2f * l1;
            float l2 = ss + eb2; l2 = l2 > 0.f ? l2 : 0.2f * l2;
            expL[n * 12 + 0 * HEADS + h] = __expf(l0);
            expL[n * 12 + 1 * HEADS + h] = __expf(l1);
            expL[n * 12 + 2 * HEADS + h] = __expf(l2);
        }
    }
}

// ---------------------------------------------------------------------------
// Phase C accumulate: block (chunk, e); bit-mask compaction + bf16 gather.
// ---------------------------------------------------------------------------
__global__ __launch_bounds__(256) void phaseC_acc(
    const unsigned char* __restrict__ HTb,   // [E, N_TOT/8] bits
    const int* __restrict__ edge_type,
    const float* __restrict__ expL,          // [N,3,4]
    const __hip_bfloat16* __restrict__ hPb,  // [N,256] bf16
    float* __restrict__ macc,                // [NCHUNK,1024,256]
    float* __restrict__ Zacc)                // [NCHUNK,1024,4]
{
    int bid = blockIdx.x;
    int chunk = bid >> 10, e = bid & 1023;
    int nbase = chunk * CHSZ;
    int j = threadIdx.x, h = j >> 6, lane = j & 63;
    int te = edge_type[e];
    __shared__ int cnt;
    __shared__ int   nidx[256];
    __shared__ float wlds[256 * 4];
    if (j == 0) cnt = 0;
    __syncthreads();
    if (j < CHSZ / 8) {
        unsigned b = HTb[(size_t)e * NTB + chunk * (CHSZ / 8) + j];
        while (b) {
            int i = __ffs(b) - 1;
            b &= b - 1;
            int p = atomicAdd(&cnt, 1);
            nidx[p] = nbase + j * 8 + i;
        }
    }
    __syncthreads();
    int c = cnt;
    for (int i = j; i < c; i += 256)
        *(float4*)&wlds[i * 4] = *(const float4*)&expL[nidx[i] * 12 + te * 4];
    __syncthreads();

    float a0 = 0.f, a1 = 0.f, a2 = 0.f, a3 = 0.f;
    float Z0 = 0.f, Z1 = 0.f, Z2 = 0.f, Z3 = 0.f;
    int i = 0;
    for (; i + 3 < c; i += 4) {
        int m0 = nidx[i], m1 = nidx[i+1], m2 = nidx[i+2], m3 = nidx[i+3];
        float w0 = wlds[i * 4 + h],     w1 = wlds[(i+1) * 4 + h];
        float w2 = wlds[(i+2) * 4 + h], w3 = wlds[(i+3) * 4 + h];
        a0 += w0 * (float)hPb[(size_t)m0 * GNN_DIM + j];
        a1 += w1 * (float)hPb[(size_t)m1 * GNN_DIM + j];
        a2 += w2 * (float)hPb[(size_t)m2 * GNN_DIM + j];
        a3 += w3 * (float)hPb[(size_t)m3 * GNN_DIM + j];
        Z0 += w0; Z1 += w1; Z2 += w2; Z3 += w3;
    }
    for (; i < c; ++i) {
        int mm = nidx[i];
        float w = wlds[i * 4 + h];
        Z0 += w;
        a0 += w * (float)hPb[(size_t)mm * GNN_DIM + j];
    }
    macc[(size_t)bid * GNN_DIM + j] = ((a0 + a1) + (a2 + a3));
    if (lane == 0) Zacc[bid * HEADS + h] = (Z0 + Z1) + (Z2 + Z3);
}

// ---------------------------------------------------------------------------
// Phase C reduce: combine NCHUNK partials, normalize, emit bf16 m + sedg.
// ---------------------------------------------------------------------------
__global__ __launch_bounds__(256) void phaseC_red(
    const float* __restrict__ macc,    // [NCHUNK,1024,256]
    const float* __restrict__ Zacc,    // [NCHUNK,1024,4]
    const float* __restrict__ aedg,    // [4,64]
    __hip_bfloat16* __restrict__ mb, float* __restrict__ sedg)
{
    int e = blockIdx.x, j = threadIdx.x, h = j >> 6, lane = j & 63;
    float s = 0.f, Z = 0.f;
    #pragma unroll
    for (int c = 0; c < NCHUNK; ++c) {
        s += macc[(size_t)((c << 10) + e) * GNN_DIM + j];
        Z += Zacc[((c << 10) + e) * HEADS + h];
    }
    float mv = s / Z;
    mb[(size_t)e * GNN_DIM + j] = __float2bfloat16(mv);
    float se = waveReduce(mv * aedg[h * DH + lane]);
    if (lane == 0) sedg[e * HEADS + h] = se;
}

// ---------------------------------------------------------------------------
// Phase E: edge->node attention + ELU + residual. One block per node.
// Bit-mask edge compaction (HNb), bf16 m gather, f32 residual.
// ---------------------------------------------------------------------------
__global__ __launch_bounds__(256) void phaseE(
    const unsigned char* __restrict__ HNb,   // [N, E/8] bits
    const float* __restrict__ sdstArr,       // [N,4]
    const float* __restrict__ sedg,          // [E,4]
    const __hip_bfloat16* __restrict__ mb,   // [E,256] bf16
    const float* __restrict__ hP,            // [N,256] residual
    float* __restrict__ hOut)
{
    int n = blockIdx.x, j = threadIdx.x, h = j >> 6;
    __shared__ int cnt;
    __shared__ int   eidx[N_EDGES];          // 4 KB
    __shared__ float wlds[N_EDGES * 4];      // 16 KB (worst case)
    __shared__ float sdv[4];
    if (j < 4) sdv[j] = sdstArr[n * HEADS + j];
    if (j == 0) cnt = 0;
    __syncthreads();
    if (j < NEB) {
        unsigned b = HNb[(size_t)n * NEB + j];
        while (b) {
            int i = __ffs(b) - 1;
            b &= b - 1;
            int p = atomicAdd(&cnt, 1);
            eidx[p] = j * 8 + i;
        }
    }
    __syncthreads();
    int c = cnt;
    for (int i = j; i < c; i += 256) {
        int e = eidx[i];
        #pragma unroll
        for (int hh = 0; hh < HEADS; ++hh) {
            float l = sdv[hh] + sedg[e * HEADS + hh];
            l = l > 0.f ? l : 0.2f * l;
            wlds[i * 4 + hh] = __expf(l);
        }
    }
    __syncthreads();

    float a0 = 0.f, a1 = 0.f, a2 = 0.f, a3 = 0.f;
    float Z0 = 0.f, Z1 = 0.f, Z2 = 0.f, Z3 = 0.f;
    int i = 0;
    for (; i + 3 < c; i += 4) {
        int e_0 = eidx[i], e_1 = eidx[i+1], e_2 = eidx[i+2], e_3 = eidx[i+3];
        float w0 = wlds[i * 4 + h],     w1 = wlds[(i+1) * 4 + h];
        float w2 = wlds[(i+2) * 4 + h], w3 = wlds[(i+3) * 4 + h];
        a0 += w0 * (float)mb[(size_t)e_0 * GNN_DIM + j];
        a1 += w1 * (float)mb[(size_t)e_1 * GNN_DIM + j];
        a2 += w2 * (float)mb[(size_t)e_2 * GNN_DIM + j];
        a3 += w3 * (float)mb[(size_t)e_3 * GNN_DIM + j];
        Z0 += w0; Z1 += w1; Z2 += w2; Z3 += w3;
    }
    for (; i < c; ++i) {
        int ee = eidx[i];
        float w = wlds[i * 4 + h];
        Z0 += w;
        a0 += w * (float)mb[(size_t)ee * GNN_DIM + j];
    }
    float Z = (Z0 + Z1) + (Z2 + Z3);
    float o = ((a0 + a1) + (a2 + a3)) / Z;
    o = o > 0.f ? o : expm1f(o);   // ELU (alpha=1)
    hOut[(size_t)n * GNN_DIM + j] = o + hP[(size_t)n * GNN_DIM + j];
}

// ---------------------------------------------------------------------------
// Final layernorms -> f32 output, concatenated [8192*256, 128*256].
// ---------------------------------------------------------------------------
__global__ __launch_bounds__(256) void finalLN(
    const float* __restrict__ hX,
    const int* __restrict__ ro_ids,
    const float* __restrict__ ng, const float* __restrict__ nb,
    const float* __restrict__ bg, const float* __restrict__ bb,
    float* __restrict__ out)
{
    int r = blockIdx.x, j = threadIdx.x;
    int srcRow; const float *g, *b; size_t outOff;
    if (r < N_PATCH) { srcRow = r; g = ng; b = nb; outOff = (size_t)r * GNN_DIM; }
    else {
        int q = r - N_PATCH;
        srcRow = ro_ids[q]; g = bg; b = bb;
        outOff = (size_t)N_PATCH * GNN_DIM + (size_t)q * GNN_DIM;
    }
    float x = hX[(size_t)srcRow * GNN_DIM + j];
    __shared__ float red[4];
    int h = j >> 6, lane = j & 63;
    float s = waveReduce(x);
    if (lane == 0) red[h] = s;
    __syncthreads();
    float mean = (red[0] + red[1] + red[2] + red[3]) * (1.f / GNN_DIM);
    __syncthreads();
    float d = x - mean;
    float s2 = waveReduce(d * d);
    if (lane == 0) red[h] = s2;
    __syncthreads();
    float var = (red[0] + red[1] + red[2] + red[3]) * (1.f / GNN_DIM);
    float y = d * rsqrtf(var + 1e-5f) * g[j] + b[j];
    out[outOff + j] = y;
}

// ---------------------------------------------------------------------------
extern "C" void kernel_launch(void* const* d_in, const int* in_sizes, int n_in,
                              void* d_out, int out_size, void* d_ws, size_t ws_size,
                              hipStream_t stream) {
    const float* x_nodes   = (const float*)d_in[0];
    const float* readout   = (const float*)d_in[1];
    const int*   node_type = (const int*)d_in[2];
    const int*   edge_type = (const int*)d_in[3];
    const float* Hmat      = (const float*)d_in[4];
    const int*   ro_ids    = (const int*)d_in[5];
    const float* W0        = (const float*)d_in[6];
    const float* W1        = (const float*)d_in[7];
    const float* node_emb  = (const float*)d_in[8];
    const float* a_src     = (const float*)d_in[9];
    const float* a_dst     = (const float*)d_in[10];
    const float* a_edge    = (const float*)d_in[11];
    const float* edge_bias = (const float*)d_in[12];
    const float* node_g    = (const float*)d_in[13];
    const float* node_b    = (const float*)d_in[14];
    const float* bag_g     = (const float*)d_in[15];
    const float* bag_b     = (const float*)d_in[16];

    // Workspace layout (~25 MB). macc aliases hX (dead during phaseC;
    // 8.39 MB <= 8.52 MB).
    char* ws = (char*)d_ws;
    size_t off = 0;
    unsigned char* HTb = (unsigned char*)(ws + off); off += (size_t)N_EDGES * NTB;   // 1.06 MB
    unsigned char* HNb = (unsigned char*)(ws + off); off += (size_t)N_TOT * NEB;     // 1.06 MB
    off = (off + 255) & ~(size_t)255;
    float* hP   = (float*)(ws + off); off += (size_t)N_TOT * GNN_DIM * 4;            // 8.52 MB
    float* hX   = (float*)(ws + off); off += (size_t)N_TOT * GNN_DIM * 4;            // 8.52 MB
    __hip_bfloat16* hPb = (__hip_bfloat16*)(ws + off); off += (size_t)N_TOT * GNN_DIM * 2; // 4.26 MB
    __hip_bfloat16* mb  = (__hip_bfloat16*)(ws + off); off += (size_t)N_EDGES * GNN_DIM * 2;
    float* expL = (float*)(ws + off); off += (size_t)N_TOT * 12 * 4;
    float* sdst = (float*)(ws + off); off += (size_t)N_TOT * HEADS * 4;
    float* sedg = (float*)(ws + off); off += (size_t)N_EDGES * HEADS * 4;
    float* Zacc = (float*)(ws + off); off += (size_t)NCHUNK * 1024 * HEADS * 4;
    float* macc = hX;  // alias (see note above)

    dim3 gT(N_TOT / 32, N_EDGES / 32);
    transposeH<<<gT, 256, 0, stream>>>(Hmat, HTb, HNb);

    // ----- layer 0 -----
    phaseA<<<N_TOT / ROWS_A, 256, 0, stream>>>(x_nodes, readout, nullptr, IN_DIM,
                                      W0, node_emb, node_type,
                                      a_src, a_dst, edge_bias,
                                      hP, hPb, expL, sdst);
    phaseC_acc<<<NCHUNK * 1024, 256, 0, stream>>>(HTb, edge_type, expL, hPb, macc, Zacc);
    phaseC_red<<<N_EDGES, 256, 0, stream>>>(macc, Zacc, a_edge, mb, sedg);
    phaseE<<<N_TOT, 256, 0, stream>>>(HNb, sdst, sedg, mb, hP, hX);

    // ----- layer 1 -----
    phaseA<<<N_TOT / ROWS_A, 256, 0, stream>>>(nullptr, nullptr, hX, GNN_DIM,
                                      W1, node_emb + 4 * GNN_DIM, node_type,
                                      a_src + HEADS * DH, a_dst + HEADS * DH,
                                      edge_bias + 12,
                                      hP, hPb, expL, sdst);
    phaseC_acc<<<NCHUNK * 1024, 256, 0, stream>>>(HTb, edge_type, expL, hPb, macc, Zacc);
    phaseC_red<<<N_EDGES, 256, 0, stream>>>(macc, Zacc, a_edge + HEADS * DH, mb, sedg);
    phaseE<<<N_TOT, 256, 0, stream>>>(HNb, sdst, sedg, mb, hP, hX);

    finalLN<<<N_TOT, 256, 0, stream>>>(hX, ro_ids, node_g, node_b, bag_g, bag_b,
                                       (float*)d_out);
}

// Round 9
// 344.111 us; speedup vs baseline: 1.1735x; 1.0423x over previous
//
#include <hip/hip_runtime.h>
#include <hip/hip_bf16.h>
#include <math.h>

// Problem constants
#define IN_DIM   384
#define GNN_DIM  256
#define HEADS    4
#define DH       64
#define N_PATCH  8192
#define N_TILES  128
#define N_EDGES  1024
#define N_TOT    (N_PATCH + N_TILES)   // 8320
#define NCHUNK   8                     // node chunks in phaseC
#define CHSZ     1040                  // nodes per chunk (8*1040 = 8320)
#define NTB      (N_TOT / 8)           // 1040 bytes per HTb row
#define NEB      (N_EDGES / 8)         // 128 bytes per HNb row

typedef short  bf16x8 __attribute__((ext_vector_type(8)));
typedef float  f32x4  __attribute__((ext_vector_type(4)));

// ---------------------------------------------------------------------------
__device__ __forceinline__ float waveReduce(float v) {
    #pragma unroll
    for (int o = 32; o > 0; o >>= 1) v += __shfl_down(v, o, 64);
    return v; // valid in lane 0 of each 64-wide wave
}

// ---------------------------------------------------------------------------
// Binarize + transpose H [N_TOT, N_EDGES] f32 into bit-packed masks:
//   HTb [E][N_TOT/8]  (edge-major, for phaseC)
//   HNb [N][N_EDGES/8] (node-major, for phaseE)
// ---------------------------------------------------------------------------
__global__ __launch_bounds__(256) void transposeH(
    const float* __restrict__ H,
    unsigned char* __restrict__ HTb, unsigned char* __restrict__ HNb)
{
    __shared__ unsigned char t[32][33];   // t[node][edge]
    int n0 = blockIdx.x * 32;
    int e0 = blockIdx.y * 32;
    int tx = threadIdx.x & 31, ty = threadIdx.x >> 5;  // ty in 0..7
    #pragma unroll
    for (int r = 0; r < 4; ++r) {
        int row = ty + r * 8;
        t[row][tx] = (H[(size_t)(n0 + row) * N_EDGES + e0 + tx] > 0.f) ? 1 : 0;
    }
    __syncthreads();
    int tid = threadIdx.x;
    if (tid < 128) {            // HTb: 32 edges x 4 node-bytes
        int er = tid >> 2, g = tid & 3;
        unsigned v = 0;
        #pragma unroll
        for (int i = 0; i < 8; ++i) v |= (unsigned)t[g * 8 + i][er] << i;
        HTb[(size_t)(e0 + er) * NTB + (n0 >> 3) + g] = (unsigned char)v;
    } else {                    // HNb: 32 nodes x 4 edge-bytes
        int id = tid - 128;
        int nr = id >> 2, g = id & 3;
        unsigned v = 0;
        #pragma unroll
        for (int i = 0; i < 8; ++i) v |= (unsigned)t[nr][g * 8 + i] << i;
        HNb[(size_t)(n0 + nr) * NEB + (e0 >> 3) + g] = (unsigned char)v;
    }
}

// ---------------------------------------------------------------------------
// castW: W [K,256] f32 -> Wt [256,K] bf16 (transposed, B^T GEMM operand)
// ---------------------------------------------------------------------------
__global__ __launch_bounds__(256) void castW(
    const float* __restrict__ W, __hip_bfloat16* __restrict__ Wt, int K)
{
    __shared__ float t[32][33];
    int k0 = blockIdx.x * 32, n0 = blockIdx.y * 32;
    int tx = threadIdx.x & 31, ty = threadIdx.x >> 5;
    #pragma unroll
    for (int r = 0; r < 4; ++r)
        t[ty + r * 8][tx] = W[(size_t)(k0 + ty + r * 8) * GNN_DIM + n0 + tx];
    __syncthreads();
    #pragma unroll
    for (int r = 0; r < 4; ++r)
        Wt[(size_t)(n0 + ty + r * 8) * K + k0 + tx] = __float2bfloat16(t[tx][ty + r * 8]);
}

// ---------------------------------------------------------------------------
// castX0: layer-0 A operand [8320,384] bf16 = concat(x_nodes, readout x128)
// ---------------------------------------------------------------------------
__global__ __launch_bounds__(256) void castX0(
    const float* __restrict__ x, const float* __restrict__ ro,
    __hip_bfloat16* __restrict__ Xb)
{
    int n = blockIdx.x;
    for (int k = threadIdx.x; k < IN_DIM; k += 256) {
        float v = (n < N_PATCH) ? x[(size_t)n * IN_DIM + k] : ro[k];
        Xb[(size_t)n * IN_DIM + k] = __float2bfloat16(v);
    }
}

// ---------------------------------------------------------------------------
// Phase A (MFMA): h = Xb @ Wt^T + nemb[node_type]; fused s_src/s_dst/expL.
// 16 rows x 256 cols per block (grid 520). Wave w owns cols [64w,64w+64)
// == head w. A-frags from LDS (padded, 16B-aligned); B-frags from global Wt
// (L2-hot). C roundtrips through LDS for the coalesced epilogue.
// ---------------------------------------------------------------------------
__global__ __launch_bounds__(256) void phaseA_mfma(
    const __hip_bfloat16* __restrict__ Xb,  // [N_TOT, K] bf16
    const __hip_bfloat16* __restrict__ Wt,  // [256, K] bf16
    int K, int KP,                          // KP = K+8 (LDS row stride)
    const float* __restrict__ nemb,
    const int* __restrict__ node_type,
    const float* __restrict__ asrc, const float* __restrict__ adst,
    const float* __restrict__ ebias,
    float* __restrict__ hP, __hip_bfloat16* __restrict__ hPb,
    float* __restrict__ expL, float* __restrict__ sdst)
{
    __shared__ char smem[16 * 260 * 4];     // 16.6 KB, union of xs / cs
    unsigned short* xs = (unsigned short*)smem;  // [16][KP] bf16 bits
    float* cs = (float*)smem;                    // [16][260] f32

    int tid = threadIdx.x;
    int n0 = blockIdx.x * 16;

    // ---- stage A-tile: 16 rows x K bf16, 16 threads per row, uint4 loads
    {
        int lr = tid >> 4, lc = tid & 15;
        for (int c = lc * 8; c < K; c += 128)
            *(uint4*)&xs[lr * KP + c] = *(const uint4*)&Xb[(size_t)(n0 + lr) * K + c];
    }
    __syncthreads();

    int wave = tid >> 6, lane = tid & 63;
    int lr16 = lane & 15, quad = lane >> 4;

    f32x4 acc[4];
    #pragma unroll
    for (int ct = 0; ct < 4; ++ct)
        acc[ct] = (f32x4){0.f, 0.f, 0.f, 0.f};

    for (int kc = 0; kc < K; kc += 32) {
        bf16x8 a = *(const bf16x8*)&xs[lr16 * KP + kc + quad * 8];
        #pragma unroll
        for (int ct = 0; ct < 4; ++ct) {
            int col = wave * 64 + ct * 16 + lr16;
            bf16x8 b = *(const bf16x8*)&Wt[(size_t)col * K + kc + quad * 8];
            acc[ct] = __builtin_amdgcn_mfma_f32_16x16x32_bf16(a, b, acc[ct], 0, 0, 0);
        }
    }
    __syncthreads();   // xs dead; reuse as cs

    // ---- C/D layout: col = lane&15, row = quad*4 + reg
    #pragma unroll
    for (int ct = 0; ct < 4; ++ct)
        #pragma unroll
        for (int g = 0; g < 4; ++g)
            cs[(quad * 4 + g) * 260 + wave * 64 + ct * 16 + lr16] = acc[ct][g];
    __syncthreads();

    // ---- epilogue: thread j <-> column j
    int j = tid, h = j >> 6, l2 = j & 63;
    float as = asrc[h * DH + l2];
    float ad = adst[h * DH + l2];
    float eb0 = ebias[0 * HEADS + h], eb1 = ebias[1 * HEADS + h], eb2 = ebias[2 * HEADS + h];
    for (int r = 0; r < 16; ++r) {
        int n = n0 + r;
        float hv = cs[r * 260 + j] + nemb[node_type[n] * GNN_DIM + j];
        hP[(size_t)n * GNN_DIM + j] = hv;
        hPb[(size_t)n * GNN_DIM + j] = __float2bfloat16(hv);
        float ss = waveReduce(hv * as);
        float sd = waveReduce(hv * ad);
        if (l2 == 0) {
            sdst[n * HEADS + h] = sd;
            float l0 = ss + eb0; l0 = l0 > 0.f ? l0 : 0.2f * l0;
            float l1 = ss + eb1; l1 = l1 > 0.f ? l1 : 0.2f * l1;
            float lc2 = ss + eb2; lc2 = lc2 > 0.f ? lc2 : 0.2f * lc2;
            expL[n * 12 + 0 * HEADS + h] = __expf(l0);
            expL[n * 12 + 1 * HEADS + h] = __expf(l1);
            expL[n * 12 + 2 * HEADS + h] = __expf(lc2);
        }
    }
}

// ---------------------------------------------------------------------------
// Phase C accumulate: block (chunk, e); bit-mask compaction + bf16 gather.
// ---------------------------------------------------------------------------
__global__ __launch_bounds__(256) void phaseC_acc(
    const unsigned char* __restrict__ HTb,   // [E, N_TOT/8] bits
    const int* __restrict__ edge_type,
    const float* __restrict__ expL,          // [N,3,4]
    const __hip_bfloat16* __restrict__ hPb,  // [N,256] bf16
    float* __restrict__ macc,                // [NCHUNK,1024,256]
    float* __restrict__ Zacc)                // [NCHUNK,1024,4]
{
    int bid = blockIdx.x;
    int chunk = bid >> 10, e = bid & 1023;
    int nbase = chunk * CHSZ;
    int j = threadIdx.x, h = j >> 6, lane = j & 63;
    int te = edge_type[e];
    __shared__ int cnt;
    __shared__ int   nidx[256];
    __shared__ float wlds[256 * 4];
    if (j == 0) cnt = 0;
    __syncthreads();
    if (j < CHSZ / 8) {
        unsigned b = HTb[(size_t)e * NTB + chunk * (CHSZ / 8) + j];
        while (b) {
            int i = __ffs(b) - 1;
            b &= b - 1;
            int p = atomicAdd(&cnt, 1);
            nidx[p] = nbase + j * 8 + i;
        }
    }
    __syncthreads();
    int c = cnt;
    for (int i = j; i < c; i += 256)
        *(float4*)&wlds[i * 4] = *(const float4*)&expL[nidx[i] * 12 + te * 4];
    __syncthreads();

    float a0 = 0.f, a1 = 0.f, a2 = 0.f, a3 = 0.f;
    float Z0 = 0.f, Z1 = 0.f, Z2 = 0.f, Z3 = 0.f;
    int i = 0;
    for (; i + 3 < c; i += 4) {
        int m0 = nidx[i], m1 = nidx[i+1], m2 = nidx[i+2], m3 = nidx[i+3];
        float w0 = wlds[i * 4 + h],     w1 = wlds[(i+1) * 4 + h];
        float w2 = wlds[(i+2) * 4 + h], w3 = wlds[(i+3) * 4 + h];
        a0 += w0 * (float)hPb[(size_t)m0 * GNN_DIM + j];
        a1 += w1 * (float)hPb[(size_t)m1 * GNN_DIM + j];
        a2 += w2 * (float)hPb[(size_t)m2 * GNN_DIM + j];
        a3 += w3 * (float)hPb[(size_t)m3 * GNN_DIM + j];
        Z0 += w0; Z1 += w1; Z2 += w2; Z3 += w3;
    }
    for (; i < c; ++i) {
        int mm = nidx[i];
        float w = wlds[i * 4 + h];
        Z0 += w;
        a0 += w * (float)hPb[(size_t)mm * GNN_DIM + j];
    }
    macc[(size_t)bid * GNN_DIM + j] = ((a0 + a1) + (a2 + a3));
    if (lane == 0) Zacc[bid * HEADS + h] = (Z0 + Z1) + (Z2 + Z3);
}

// ---------------------------------------------------------------------------
// Phase C reduce: combine NCHUNK partials, normalize, emit bf16 m + sedg.
// ---------------------------------------------------------------------------
__global__ __launch_bounds__(256) void phaseC_red(
    const float* __restrict__ macc,    // [NCHUNK,1024,256]
    const float* __restrict__ Zacc,    // [NCHUNK,1024,4]
    const float* __restrict__ aedg,    // [4,64]
    __hip_bfloat16* __restrict__ mb, float* __restrict__ sedg)
{
    int e = blockIdx.x, j = threadIdx.x, h = j >> 6, lane = j & 63;
    float s = 0.f, Z = 0.f;
    #pragma unroll
    for (int c = 0; c < NCHUNK; ++c) {
        s += macc[(size_t)((c << 10) + e) * GNN_DIM + j];
        Z += Zacc[((c << 10) + e) * HEADS + h];
    }
    float mv = s / Z;
    mb[(size_t)e * GNN_DIM + j] = __float2bfloat16(mv);
    float se = waveReduce(mv * aedg[h * DH + lane]);
    if (lane == 0) sedg[e * HEADS + h] = se;
}

// ---------------------------------------------------------------------------
// Phase E: edge->node attention + ELU + residual. One block per node.
// Bit-mask edge compaction (HNb), bf16 m gather, f32 residual.
// Emits f32 hOut and bf16 hOutb (next layer's GEMM A operand).
// ---------------------------------------------------------------------------
__global__ __launch_bounds__(256) void phaseE(
    const unsigned char* __restrict__ HNb,   // [N, E/8] bits
    const float* __restrict__ sdstArr,       // [N,4]
    const float* __restrict__ sedg,          // [E,4]
    const __hip_bfloat16* __restrict__ mb,   // [E,256] bf16
    const float* __restrict__ hP,            // [N,256] residual
    float* __restrict__ hOut, __hip_bfloat16* __restrict__ hOutb)
{
    int n = blockIdx.x, j = threadIdx.x, h = j >> 6;
    __shared__ int cnt;
    __shared__ int   eidx[N_EDGES];          // 4 KB
    __shared__ float wlds[N_EDGES * 4];      // 16 KB (worst case)
    __shared__ float sdv[4];
    if (j < 4) sdv[j] = sdstArr[n * HEADS + j];
    if (j == 0) cnt = 0;
    __syncthreads();
    if (j < NEB) {
        unsigned b = HNb[(size_t)n * NEB + j];
        while (b) {
            int i = __ffs(b) - 1;
            b &= b - 1;
            int p = atomicAdd(&cnt, 1);
            eidx[p] = j * 8 + i;
        }
    }
    __syncthreads();
    int c = cnt;
    for (int i = j; i < c; i += 256) {
        int e = eidx[i];
        #pragma unroll
        for (int hh = 0; hh < HEADS; ++hh) {
            float l = sdv[hh] + sedg[e * HEADS + hh];
            l = l > 0.f ? l : 0.2f * l;
            wlds[i * 4 + hh] = __expf(l);
        }
    }
    __syncthreads();

    float a0 = 0.f, a1 = 0.f, a2 = 0.f, a3 = 0.f;
    float Z0 = 0.f, Z1 = 0.f, Z2 = 0.f, Z3 = 0.f;
    int i = 0;
    for (; i + 3 < c; i += 4) {
        int e_0 = eidx[i], e_1 = eidx[i+1], e_2 = eidx[i+2], e_3 = eidx[i+3];
        float w0 = wlds[i * 4 + h],     w1 = wlds[(i+1) * 4 + h];
        float w2 = wlds[(i+2) * 4 + h], w3 = wlds[(i+3) * 4 + h];
        a0 += w0 * (float)mb[(size_t)e_0 * GNN_DIM + j];
        a1 += w1 * (float)mb[(size_t)e_1 * GNN_DIM + j];
        a2 += w2 * (float)mb[(size_t)e_2 * GNN_DIM + j];
        a3 += w3 * (float)mb[(size_t)e_3 * GNN_DIM + j];
        Z0 += w0; Z1 += w1; Z2 += w2; Z3 += w3;
    }
    for (; i < c; ++i) {
        int ee = eidx[i];
        float w = wlds[i * 4 + h];
        Z0 += w;
        a0 += w * (float)mb[(size_t)ee * GNN_DIM + j];
    }
    float Z = (Z0 + Z1) + (Z2 + Z3);
    float o = ((a0 + a1) + (a2 + a3)) / Z;
    o = o > 0.f ? o : expm1f(o);   // ELU (alpha=1)
    float res = o + hP[(size_t)n * GNN_DIM + j];
    hOut[(size_t)n * GNN_DIM + j] = res;
    hOutb[(size_t)n * GNN_DIM + j] = __float2bfloat16(res);
}

// ---------------------------------------------------------------------------
// Final layernorms -> f32 output, concatenated [8192*256, 128*256].
// ---------------------------------------------------------------------------
__global__ __launch_bounds__(256) void finalLN(
    const float* __restrict__ hX,
    const int* __restrict__ ro_ids,
    const float* __restrict__ ng, const float* __restrict__ nb,
    const float* __restrict__ bg, const float* __restrict__ bb,
    float* __restrict__ out)
{
    int r = blockIdx.x, j = threadIdx.x;
    int srcRow; const float *g, *b; size_t outOff;
    if (r < N_PATCH) { srcRow = r; g = ng; b = nb; outOff = (size_t)r * GNN_DIM; }
    else {
        int q = r - N_PATCH;
        srcRow = ro_ids[q]; g = bg; b = bb;
        outOff = (size_t)N_PATCH * GNN_DIM + (size_t)q * GNN_DIM;
    }
    float x = hX[(size_t)srcRow * GNN_DIM + j];
    __shared__ float red[4];
    int h = j >> 6, lane = j & 63;
    float s = waveReduce(x);
    if (lane == 0) red[h] = s;
    __syncthreads();
    float mean = (red[0] + red[1] + red[2] + red[3]) * (1.f / GNN_DIM);
    __syncthreads();
    float d = x - mean;
    float s2 = waveReduce(d * d);
    if (lane == 0) red[h] = s2;
    __syncthreads();
    float var = (red[0] + red[1] + red[2] + red[3]) * (1.f / GNN_DIM);
    float y = d * rsqrtf(var + 1e-5f) * g[j] + b[j];
    out[outOff + j] = y;
}

// ---------------------------------------------------------------------------
extern "C" void kernel_launch(void* const* d_in, const int* in_sizes, int n_in,
                              void* d_out, int out_size, void* d_ws, size_t ws_size,
                              hipStream_t stream) {
    const float* x_nodes   = (const float*)d_in[0];
    const float* readout   = (const float*)d_in[1];
    const int*   node_type = (const int*)d_in[2];
    const int*   edge_type = (const int*)d_in[3];
    const float* Hmat      = (const float*)d_in[4];
    const int*   ro_ids    = (const int*)d_in[5];
    const float* W0        = (const float*)d_in[6];
    const float* W1        = (const float*)d_in[7];
    const float* node_emb  = (const float*)d_in[8];
    const float* a_src     = (const float*)d_in[9];
    const float* a_dst     = (const float*)d_in[10];
    const float* a_edge    = (const float*)d_in[11];
    const float* edge_bias = (const float*)d_in[12];
    const float* node_g    = (const float*)d_in[13];
    const float* node_b    = (const float*)d_in[14];
    const float* bag_g     = (const float*)d_in[15];
    const float* bag_b     = (const float*)d_in[16];

    // Workspace layout (~31 MB). Aliases:
    //   macc = hX  (hX dead during phaseC; 8.39 MB <= 8.52 MB)
    //   hXb  = Xb0 (Xb0 dead after layer-0 phaseA; 4.26 MB <= 6.39 MB)
    char* ws = (char*)d_ws;
    size_t off = 0;
    unsigned char* HTb = (unsigned char*)(ws + off); off += (size_t)N_EDGES * NTB;   // 1.06 MB
    unsigned char* HNb = (unsigned char*)(ws + off); off += (size_t)N_TOT * NEB;     // 1.06 MB
    off = (off + 255) & ~(size_t)255;
    float* hP   = (float*)(ws + off); off += (size_t)N_TOT * GNN_DIM * 4;            // 8.52 MB
    float* hX   = (float*)(ws + off); off += (size_t)N_TOT * GNN_DIM * 4;            // 8.52 MB
    __hip_bfloat16* hPb = (__hip_bfloat16*)(ws + off); off += (size_t)N_TOT * GNN_DIM * 2; // 4.26 MB
    __hip_bfloat16* mb  = (__hip_bfloat16*)(ws + off); off += (size_t)N_EDGES * GNN_DIM * 2;
    __hip_bfloat16* Xb0 = (__hip_bfloat16*)(ws + off); off += (size_t)N_TOT * IN_DIM * 2;  // 6.39 MB
    __hip_bfloat16* Wt0 = (__hip_bfloat16*)(ws + off); off += (size_t)GNN_DIM * IN_DIM * 2;
    __hip_bfloat16* Wt1 = (__hip_bfloat16*)(ws + off); off += (size_t)GNN_DIM * GNN_DIM * 2;
    float* expL = (float*)(ws + off); off += (size_t)N_TOT * 12 * 4;
    float* sdst = (float*)(ws + off); off += (size_t)N_TOT * HEADS * 4;
    float* sedg = (float*)(ws + off); off += (size_t)N_EDGES * HEADS * 4;
    float* Zacc = (float*)(ws + off); off += (size_t)NCHUNK * 1024 * HEADS * 4;
    float* macc = hX;                        // alias
    __hip_bfloat16* hXb = Xb0;               // alias

    // ----- prep -----
    castW<<<dim3(IN_DIM / 32, GNN_DIM / 32), 256, 0, stream>>>(W0, Wt0, IN_DIM);
    castW<<<dim3(GNN_DIM / 32, GNN_DIM / 32), 256, 0, stream>>>(W1, Wt1, GNN_DIM);
    castX0<<<N_TOT, 256, 0, stream>>>(x_nodes, readout, Xb0);
    dim3 gT(N_TOT / 32, N_EDGES / 32);
    transposeH<<<gT, 256, 0, stream>>>(Hmat, HTb, HNb);

    // ----- layer 0 -----
    phaseA_mfma<<<N_TOT / 16, 256, 0, stream>>>(Xb0, Wt0, IN_DIM, IN_DIM + 8,
                                      node_emb, node_type,
                                      a_src, a_dst, edge_bias,
                                      hP, hPb, expL, sdst);
    phaseC_acc<<<NCHUNK * 1024, 256, 0, stream>>>(HTb, edge_type, expL, hPb, macc, Zacc);
    phaseC_red<<<N_EDGES, 256, 0, stream>>>(macc, Zacc, a_edge, mb, sedg);
    phaseE<<<N_TOT, 256, 0, stream>>>(HNb, sdst, sedg, mb, hP, hX, hXb);

    // ----- layer 1 -----
    phaseA_mfma<<<N_TOT / 16, 256, 0, stream>>>(hXb, Wt1, GNN_DIM, GNN_DIM + 8,
                                      node_emb + 4 * GNN_DIM, node_type,
                                      a_src + HEADS * DH, a_dst + HEADS * DH,
                                      edge_bias + 12,
                                      hP, hPb, expL, sdst);
    phaseC_acc<<<NCHUNK * 1024, 256, 0, stream>>>(HTb, edge_type, expL, hPb, macc, Zacc);
    phaseC_red<<<N_EDGES, 256, 0, stream>>>(macc, Zacc, a_edge + HEADS * DH, mb, sedg);
    phaseE<<<N_TOT, 256, 0, stream>>>(HNb, sdst, sedg, mb, hP, hX, hXb);

    finalLN<<<N_TOT, 256, 0, stream>>>(hX, ro_ids, node_g, node_b, bag_g, bag_b,
                                       (float*)d_out);
}